// Round 12
// baseline (126.595 us; speedup 1.0000x reference)
//
#include <hip/hip_runtime.h>

typedef __bf16 bf16_t;
typedef __bf16 bf16x8 __attribute__((ext_vector_type(8)));
typedef __bf16 bf16x4 __attribute__((ext_vector_type(4)));
typedef float f32x4 __attribute__((ext_vector_type(4)));
typedef int   i32x4 __attribute__((ext_vector_type(4)));

#define HH 96
#define WW 96
#define CC 128
#define HD 32
#define TOK (HH * WW)      // 9216
#define PLANE (TOK * CC)
#define KW 7

// bf16 weight slab offsets (elements) in ws
#define W_QKV  0
#define W_PROJ 49152
#define W_FC1  65536
#define W_FC2  131072
#define W_TOT  196608

#define PATCH 10
#define PSZ 100
#define NPAD 112            // 7 N-tiles of 16
#define STR 136             // LDS row stride (bf16)
#define H1S 520

// fp32 -> bf16x8
__device__ __forceinline__ bf16x8 cvt8(const float* __restrict__ p) {
    const f32x4 a = *(const f32x4*)p;
    const f32x4 b = *(const f32x4*)(p + 4);
    bf16x8 r;
    r[0] = (bf16_t)a[0]; r[1] = (bf16_t)a[1]; r[2] = (bf16_t)a[2]; r[3] = (bf16_t)a[3];
    r[4] = (bf16_t)b[0]; r[5] = (bf16_t)b[1]; r[6] = (bf16_t)b[2]; r[7] = (bf16_t)b[3];
    return r;
}

// NT-tile MFMA strip (bf16 A/W, K-contiguous rows, at tile origin).
// A-frag: lane holds A[lane&15][(lane>>4)*8+j]; B-frag: W[t*16+(lane&15)][...]
// C/D: reg r -> row (lane>>4)*4+r, col t*16+(lane&15)
template <int NT>
__device__ __forceinline__ void mmaN(const bf16_t* __restrict__ A, int lda,
                                     const bf16_t* __restrict__ W, int ldb,
                                     int K, f32x4* acc) {
    const int lane = threadIdx.x & 63;
    const bf16_t* ap = A + (lane & 15) * lda + ((lane >> 4) * 8);
    const bf16_t* bp = W + (lane & 15) * ldb + ((lane >> 4) * 8);
    for (int k0 = 0; k0 < K; k0 += 32) {
        bf16x8 a = *(const bf16x8*)(ap + k0);
#pragma unroll
        for (int t = 0; t < NT; t++) {
            bf16x8 b = *(const bf16x8*)(bp + t * 16 * ldb + k0);
            acc[t] = __builtin_amdgcn_mfma_f32_16x16x32_bf16(a, b, acc[t], 0, 0, 0);
        }
    }
}

// K1: convert all 4 fp32 weight mats -> bf16 slab. 192 blocks.
__global__ __launch_bounds__(256) void k_cvt(const float* __restrict__ qkv_w,
                                             const float* __restrict__ proj_w,
                                             const float* __restrict__ fc1_w,
                                             const float* __restrict__ fc2_w,
                                             bf16_t* __restrict__ wb) {
    const int base = (blockIdx.x * 256 + threadIdx.x) * 4;   // 49152 chunks
    const float* src;
    if (base < W_PROJ)     src = qkv_w  + base;
    else if (base < W_FC1) src = proj_w + (base - W_PROJ);
    else if (base < W_FC2) src = fc1_w  + (base - W_FC1);
    else                   src = fc2_w  + (base - W_FC2);
    const f32x4 a = *(const f32x4*)src;
    bf16x4 r;
    r[0] = (bf16_t)a[0]; r[1] = (bf16_t)a[1]; r[2] = (bf16_t)a[2]; r[3] = (bf16_t)a[3];
    *(bf16x4*)(wb + base) = r;
}

// K2: qkv = x @ qkv_w.T + b. 1728 blocks, 6912 waves (6.75/SIMD).
// wave = 16 tokens x 32 cols (NT=2, 8 MFMA) — fine-grained for latency hiding.
__global__ __launch_bounds__(256) void k_qkv(const float* __restrict__ x,
                                             const bf16_t* __restrict__ wb,
                                             const float* __restrict__ bias,
                                             bf16_t* __restrict__ qb,
                                             bf16_t* __restrict__ kb,
                                             bf16_t* __restrict__ vb) {
    const int wid = blockIdx.x * 4 + (threadIdx.x >> 6);   // 6912 waves
    const int m0 = (wid / 12) * 16;
    const int n0 = (wid % 12) * 32;
    const int lane = threadIdx.x & 63;
    const int g = lane >> 4, li = lane & 15;
    const float* ap = x + (m0 + li) * CC + g * 8;
    const bf16_t* bp = wb + W_QKV + (n0 + li) * CC + g * 8;
    f32x4 acc[2] = {};
    for (int k0 = 0; k0 < CC; k0 += 32) {
        bf16x8 a = cvt8(ap + k0);
#pragma unroll
        for (int t = 0; t < 2; t++) {
            bf16x8 b = *(const bf16x8*)(bp + t * 16 * CC + k0);
            acc[t] = __builtin_amdgcn_mfma_f32_16x16x32_bf16(a, b, acc[t], 0, 0, 0);
        }
    }
#pragma unroll
    for (int t = 0; t < 2; t++) {
        const int n = n0 + t * 16 + li;
        const float bb = bias[n];
        const int part = n >> 7, c = n & 127;
        bf16_t* dst = (part == 0) ? qb : (part == 1) ? kb : vb;
#pragma unroll
        for (int r = 0; r < 4; r++)
            dst[(m0 + g * 4 + r) * CC + c] = (bf16_t)(acc[t][r] + bb);
    }
}

// K3: na2d + proj per 4x4-token tile, 576 blocks, one wave per head.
// Patch->byte-offset LDS table kills all runtime /10 %10 address math.
__global__ __launch_bounds__(256, 4) void k_attn(
        const bf16_t* __restrict__ qb, const bf16_t* __restrict__ kg,
        const bf16_t* __restrict__ vg, const bf16_t* __restrict__ wb,
        const float* __restrict__ proj_b, bf16_t* __restrict__ x0g) {
    __shared__ __align__(16) bf16_t Pbuf[4 * 16 * STR];   // 17408 B
    __shared__ __align__(16) bf16_t o_s[16 * STR];        //  4352 B
    __shared__ __align__(16) int voff[128];               // patch idx -> elem offset

    const int tid = threadIdx.x;
    const int w = tid >> 6, lane = tid & 63;
    const int g = lane >> 4, li = lane & 15;
    const int bid = blockIdx.x;
    const int i0 = (bid / 24) * 4, j0 = (bid % 24) * 4;
    const int pr0 = min(max(i0 - 3, 0), HH - PATCH);
    const int pc0 = min(max(j0 - 3, 0), WW - PATCH);
    const int head = w;
    const int ch = head * HD;

    if (tid < 128) {
        const int p = min(tid, PSZ - 1);       // pads clamp to row 99 (masked)
        const int pi = p / 10, pj = p - 10 * pi;
        voff[tid] = ((pr0 + pi) * WW + pc0 + pj) * CC;
    }
    __syncthreads();

    // ---- phase 1: logits[16][112] = Q @ K^T, direct-global fragments ----
    f32x4 lg[7];
    {
        const int qi = i0 + (li >> 2), qj = j0 + (li & 3);
        const bf16x8 aq = *(const bf16x8*)(qb + (qi * WW + qj) * CC + ch + g * 8);
#pragma unroll
        for (int t = 0; t < 7; t++) {
            const bf16x8 bk = *(const bf16x8*)(kg + voff[t * 16 + li] + ch + g * 8);
            lg[t] = __builtin_amdgcn_mfma_f32_16x16x32_bf16(aq, bk, (f32x4){0.f,0.f,0.f,0.f}, 0, 0, 0);
        }
    }
    // ---- mask + register softmax (row m=g*4+r, col nb=t*16+li) ----
    int lr[4], lc[4];
#pragma unroll
    for (int r = 0; r < 4; r++) {
        const int m = g * 4 + r;
        const int i = i0 + (m >> 2), j = j0 + (m & 3);
        lr[r] = min(max(i - 3, 0), HH - KW) - pr0;
        lc[r] = min(max(j - 3, 0), WW - KW) - pc0;
    }
    const float scale = 0.17677669529663687f;   // 1/sqrt(32)
#pragma unroll
    for (int t = 0; t < 7; t++) {
        const int col = t * 16 + li;
        const int pi = col / 10, pj = col - 10 * pi;   // compile-time-ish (li only)
#pragma unroll
        for (int r = 0; r < 4; r++) {
            const bool valid = (col < PSZ) &&
                               ((unsigned)(pi - lr[r]) <= 6u) &&
                               ((unsigned)(pj - lc[r]) <= 6u);
            lg[t][r] = valid ? lg[t][r] * scale : -1e30f;
        }
    }
    f32x4 mx = lg[0], sm;
#pragma unroll
    for (int t = 1; t < 7; t++)
#pragma unroll
        for (int r = 0; r < 4; r++) mx[r] = fmaxf(mx[r], lg[t][r]);
#pragma unroll
    for (int off = 8; off; off >>= 1)
#pragma unroll
        for (int r = 0; r < 4; r++) mx[r] = fmaxf(mx[r], __shfl_xor(mx[r], off));
#pragma unroll
    for (int r = 0; r < 4; r++) sm[r] = 0.f;
#pragma unroll
    for (int t = 0; t < 7; t++)
#pragma unroll
        for (int r = 0; r < 4; r++) {
            lg[t][r] = __expf(lg[t][r] - mx[r]);
            sm[r] += lg[t][r];
        }
#pragma unroll
    for (int off = 8; off; off >>= 1)
#pragma unroll
        for (int r = 0; r < 4; r++) sm[r] += __shfl_xor(sm[r], off);
#pragma unroll
    for (int r = 0; r < 4; r++) sm[r] = 1.f / sm[r];

    // ---- P bf16 -> per-wave Pbuf (cols 112..127 zeroed) ----
    bf16_t* Pw = Pbuf + w * 16 * STR;
#pragma unroll
    for (int t = 0; t < 7; t++)
#pragma unroll
        for (int r = 0; r < 4; r++)
            Pw[(g * 4 + r) * STR + t * 16 + li] = (bf16_t)(lg[t][r] * sm[r]);
    *(bf16x4*)(Pw + (lane >> 2) * STR + NPAD + (lane & 3) * 4) = (bf16x4){0,0,0,0};
    __syncthreads();

    // ---- phase 2: O[16][32] = P @ V^T; offsets from table (b128 reads) ----
    f32x4 oA[2] = {};
#pragma unroll
    for (int ks0 = 0; ks0 < 128; ks0 += 32) {
        const bf16x8 a = *(const bf16x8*)(Pw + li * STR + ks0 + g * 8);
        const i32x4 o0 = *(const i32x4*)&voff[ks0 + g * 8];
        const i32x4 o1 = *(const i32x4*)&voff[ks0 + g * 8 + 4];
#pragma unroll
        for (int t2 = 0; t2 < 2; t2++) {
            const int cb = ch + t2 * 16 + li;
            bf16x8 b;
            b[0] = vg[o0[0] + cb]; b[1] = vg[o0[1] + cb];
            b[2] = vg[o0[2] + cb]; b[3] = vg[o0[3] + cb];
            b[4] = vg[o1[0] + cb]; b[5] = vg[o1[1] + cb];
            b[6] = vg[o1[2] + cb]; b[7] = vg[o1[3] + cb];
            oA[t2] = __builtin_amdgcn_mfma_f32_16x16x32_bf16(a, b, oA[t2], 0, 0, 0);
        }
    }
    // ---- o -> LDS [16][STR] (cols ch..ch+31) ----
#pragma unroll
    for (int t2 = 0; t2 < 2; t2++)
#pragma unroll
        for (int r = 0; r < 4; r++)
            o_s[(g * 4 + r) * STR + ch + t2 * 16 + li] = (bf16_t)oA[t2][r];
    __syncthreads();

    // ---- proj: x0[16][128] = o @ proj_w^T + b; wave w -> cols w*32.. ----
    {
        f32x4 acc[2] = {};
        mmaN<2>(o_s, STR, wb + W_PROJ + (w * 32) * CC, CC, CC, acc);
#pragma unroll
        for (int t = 0; t < 2; t++) {
            const int n = w * 32 + t * 16 + li;
            const float bb = proj_b[n];
#pragma unroll
            for (int r = 0; r < 4; r++) {
                const int m = g * 4 + r;
                const int i = i0 + (m >> 2), j = j0 + (m & 3);
                x0g[(i * WW + j) * CC + n] = (bf16_t)(acc[t][r] + bb);
            }
        }
    }
}

// K4: MLP per 16 token rows, 512-thread blocks (8 waves), 576 blocks.
// fc1: wave w -> 64 cols (NT=4). fc2: wave w -> 16 cols (NT=1, K=512).
__global__ __launch_bounds__(512, 4) void k_mlp(const bf16_t* __restrict__ x0g,
                                                const bf16_t* __restrict__ wb,
                                                const float* __restrict__ fc1_b,
                                                const float* __restrict__ fc2_b,
                                                float* __restrict__ out) {
    __shared__ __align__(16) bf16_t h1s[16 * H1S];   // 16640 B
    const int w = threadIdx.x >> 6, lane = threadIdx.x & 63;
    const int g = lane >> 4, li = lane & 15;
    const int m0 = blockIdx.x * 16;

    {   // fc1 + gelu: wave w -> h1 cols [w*64, w*64+64)
        f32x4 acc[4] = {};
        mmaN<4>(x0g + m0 * CC, CC, wb + W_FC1 + (w * 64) * CC, CC, CC, acc);
#pragma unroll
        for (int t = 0; t < 4; t++) {
            const int n = w * 64 + t * 16 + li;
            const float bb = fc1_b[n];
#pragma unroll
            for (int r = 0; r < 4; r++) {
                const int m = g * 4 + r;
                const float xv = acc[t][r] + bb;
                const float u = 0.7978845608028654f * (xv + 0.044715f * xv * xv * xv);
                const float e = __expf(2.f * u);
                const float gg = 0.5f * xv * (2.f - 2.f / (e + 1.f));
                h1s[m * H1S + n] = (bf16_t)gg;
            }
        }
    }
    __syncthreads();
    {   // fc2: wave w -> out cols [w*16, w*16+16), K=512 from LDS
        f32x4 acc[1] = {};
        mmaN<1>(h1s, H1S, wb + W_FC2 + (w * 16) * (4 * CC), 4 * CC, 4 * CC, acc);
        const int n = w * 16 + li;
        const float bb = fc2_b[n];
#pragma unroll
        for (int r = 0; r < 4; r++) {
            const int m = g * 4 + r;
            float xv = acc[0][r] + bb;
            xv = fminf(fmaxf(xv, -1e4f), 1e4f);   // diagnostic clamp
            out[(m0 + m) * CC + n] = xv;
        }
    }
}

extern "C" void kernel_launch(void* const* d_in, const int* in_sizes, int n_in,
                              void* d_out, int out_size, void* d_ws, size_t ws_size,
                              hipStream_t stream) {
    const float* x      = (const float*)d_in[0];
    const float* qkv_w  = (const float*)d_in[1];
    const float* qkv_b  = (const float*)d_in[2];
    const float* proj_w = (const float*)d_in[3];
    const float* proj_b = (const float*)d_in[4];
    const float* fc1_w  = (const float*)d_in[5];
    const float* fc1_b  = (const float*)d_in[6];
    const float* fc2_w  = (const float*)d_in[7];
    const float* fc2_b  = (const float*)d_in[8];

    bf16_t* ws = (bf16_t*)d_ws;
    bf16_t* qb = ws;                  // [9216][128] bf16
    bf16_t* kb = ws + PLANE;
    bf16_t* vb = ws + 2 * PLANE;
    bf16_t* x0 = ws + 3 * PLANE;
    bf16_t* wb = ws + 4 * PLANE;      // 196608-elem bf16 weight slab
    float* out = (float*)d_out;

    k_cvt <<<192,  256, 0, stream>>>(qkv_w, proj_w, fc1_w, fc2_w, wb);
    k_qkv <<<1728, 256, 0, stream>>>(x, wb, qkv_b, qb, kb, vb);
    k_attn<<<576,  256, 0, stream>>>(qb, kb, vb, wb, proj_b, x0);
    k_mlp <<<576,  512, 0, stream>>>(x0, wb, fc1_b, fc2_b, out);
}

// Round 13
// 122.422 us; speedup vs baseline: 1.0341x; 1.0341x over previous
//
#include <hip/hip_runtime.h>

typedef __bf16 bf16_t;
typedef __bf16 bf16x8 __attribute__((ext_vector_type(8)));
typedef __bf16 bf16x4 __attribute__((ext_vector_type(4)));
typedef float f32x4 __attribute__((ext_vector_type(4)));
typedef int   i32x4 __attribute__((ext_vector_type(4)));

#define HH 96
#define WW 96
#define CC 128
#define HD 32
#define TOK (HH * WW)      // 9216
#define PLANE (TOK * CC)
#define KW 7

// bf16 weight slab (ws): proj, fc1, fc2 (qkv weights consumed fp32-inline)
#define W_PROJ 0
#define W_FC1  16384
#define W_FC2  81920
#define W_TOT  147456

#define PATCH 10
#define PSZ 100
#define NPAD 112            // 7 N-tiles of 16
#define STR 136             // LDS row stride (bf16)
#define H1S 520

// K2 LDS layout (bf16 elements):
//   Pbuf  @0      4*16*STR = 8704 ele (17408 B) -> h1s @0 (16*H1S = 8320 ele)
//   o_s   @8704   16*STR = 2176 ele
//   x0s   @10880  16*STR = 2176 ele
//   voff  @13056  128 ints = 256 ele
#define L_P    0
#define L_OS   8704
#define L_X0   10880
#define L_VOFF 13056
#define L_TOT  13312        // 26624 B -> >=3 blocks/CU

// fp32 -> bf16x8
__device__ __forceinline__ bf16x8 cvt8(const float* __restrict__ p) {
    const f32x4 a = *(const f32x4*)p;
    const f32x4 b = *(const f32x4*)(p + 4);
    bf16x8 r;
    r[0] = (bf16_t)a[0]; r[1] = (bf16_t)a[1]; r[2] = (bf16_t)a[2]; r[3] = (bf16_t)a[3];
    r[4] = (bf16_t)b[0]; r[5] = (bf16_t)b[1]; r[6] = (bf16_t)b[2]; r[7] = (bf16_t)b[3];
    return r;
}

// NT-tile MFMA strip (bf16 A/W, K-contiguous rows, at tile origin).
// A-frag: lane holds A[lane&15][(lane>>4)*8+j]; B-frag: W[t*16+(lane&15)][...]
// C/D: reg r -> row (lane>>4)*4+r, col t*16+(lane&15)
template <int NT>
__device__ __forceinline__ void mmaN(const bf16_t* __restrict__ A, int lda,
                                     const bf16_t* __restrict__ W, int ldb,
                                     int K, f32x4* acc) {
    const int lane = threadIdx.x & 63;
    const bf16_t* ap = A + (lane & 15) * lda + ((lane >> 4) * 8);
    const bf16_t* bp = W + (lane & 15) * ldb + ((lane >> 4) * 8);
    for (int k0 = 0; k0 < K; k0 += 32) {
        bf16x8 a = *(const bf16x8*)(ap + k0);
#pragma unroll
        for (int t = 0; t < NT; t++) {
            bf16x8 b = *(const bf16x8*)(bp + t * 16 * ldb + k0);
            acc[t] = __builtin_amdgcn_mfma_f32_16x16x32_bf16(a, b, acc[t], 0, 0, 0);
        }
    }
}

// ===========================================================================
// K1: [first 144 blocks: cvt proj/fc1/fc2 -> bf16 slab] + qkv GEMM with
// fp32 weights inline. 864 blocks x 256. q/k/v bf16 planes [tok][128].
// ===========================================================================
__global__ __launch_bounds__(256) void k_qkv(const float* __restrict__ x,
                                             const float* __restrict__ qkv_w,
                                             const float* __restrict__ qkv_b,
                                             const float* __restrict__ proj_w,
                                             const float* __restrict__ fc1_w,
                                             const float* __restrict__ fc2_w,
                                             bf16_t* __restrict__ wb,
                                             bf16_t* __restrict__ qb,
                                             bf16_t* __restrict__ kb,
                                             bf16_t* __restrict__ vb) {
    const int tid = threadIdx.x, bid = blockIdx.x;
    {   // slab cvt: 36864 x4-chunks over blocks 0..143
        const int idx = bid * 256 + tid;
        if (idx < W_TOT / 4) {
            const int base = idx * 4;
            const float* src;
            if (base < W_FC1)      src = proj_w + base;
            else if (base < W_FC2) src = fc1_w + (base - W_FC1);
            else                   src = fc2_w + (base - W_FC2);
            const f32x4 a = *(const f32x4*)src;
            bf16x4 r;
            r[0] = (bf16_t)a[0]; r[1] = (bf16_t)a[1];
            r[2] = (bf16_t)a[2]; r[3] = (bf16_t)a[3];
            *(bf16x4*)(wb + base) = r;
        }
    }
    // qkv GEMM: wave = 16 tokens x 64 cols (NT=4), 3456 waves
    const int wid = bid * 4 + (tid >> 6);
    const int m0 = (wid / 6) * 16;
    const int n0 = (wid % 6) * 64;
    const int lane = tid & 63;
    const int g = lane >> 4, li = lane & 15;
    const float* ap = x + (m0 + li) * CC + g * 8;
    const float* bp = qkv_w + (n0 + li) * CC + g * 8;
    f32x4 acc[4] = {};
    for (int k0 = 0; k0 < CC; k0 += 32) {
        bf16x8 a = cvt8(ap + k0);
#pragma unroll
        for (int t = 0; t < 4; t++) {
            bf16x8 b = cvt8(bp + t * 16 * CC + k0);
            acc[t] = __builtin_amdgcn_mfma_f32_16x16x32_bf16(a, b, acc[t], 0, 0, 0);
        }
    }
#pragma unroll
    for (int t = 0; t < 4; t++) {
        const int n = n0 + t * 16 + li;
        const float bb = qkv_b[n];
        const int part = n >> 7, c = n & 127;
        bf16_t* dst = (part == 0) ? qb : (part == 1) ? kb : vb;
#pragma unroll
        for (int r = 0; r < 4; r++)
            dst[(m0 + g * 4 + r) * CC + c] = (bf16_t)(acc[t][r] + bb);
    }
}

// ===========================================================================
// K2: attn + proj + MLP per 4x4-token tile. 576 blocks x 256, one wave/head.
// Direct-global K/V fragments via voff table; x0 never leaves LDS.
// ===========================================================================
__global__ __launch_bounds__(256, 3) void k_attn_mlp(
        const bf16_t* __restrict__ qb, const bf16_t* __restrict__ kg,
        const bf16_t* __restrict__ vg, const bf16_t* __restrict__ wb,
        const float* __restrict__ proj_b, const float* __restrict__ fc1_b,
        const float* __restrict__ fc2_b,  float* __restrict__ out) {
    __shared__ __align__(16) bf16_t smem[L_TOT];
    bf16_t* Pbuf = smem + L_P;
    bf16_t* o_s  = smem + L_OS;
    bf16_t* x0s  = smem + L_X0;
    bf16_t* h1s  = smem + L_P;          // overlays Pbuf after barrier 2
    int*    voff = (int*)(smem + L_VOFF);

    const int tid = threadIdx.x;
    const int w = tid >> 6, lane = tid & 63;
    const int g = lane >> 4, li = lane & 15;
    const int bid = blockIdx.x;
    const int i0 = (bid / 24) * 4, j0 = (bid % 24) * 4;
    const int pr0 = min(max(i0 - 3, 0), HH - PATCH);
    const int pc0 = min(max(j0 - 3, 0), WW - PATCH);
    const int ch = w * HD;              // head channel base

    if (tid < 128) {
        const int p = min(tid, PSZ - 1);       // pads clamp to row 99 (masked)
        const int pi = p / 10, pj = p - 10 * pi;
        voff[tid] = ((pr0 + pi) * WW + pc0 + pj) * CC;
    }
    __syncthreads();                    // B1: voff ready

    // ---- attn phase 1: logits[16][112] = Q @ K^T ----
    f32x4 lg[7];
    {
        const int qi = i0 + (li >> 2), qj = j0 + (li & 3);
        const bf16x8 aq = *(const bf16x8*)(qb + (qi * WW + qj) * CC + ch + g * 8);
#pragma unroll
        for (int t = 0; t < 7; t++) {
            const bf16x8 bk = *(const bf16x8*)(kg + voff[t * 16 + li] + ch + g * 8);
            lg[t] = __builtin_amdgcn_mfma_f32_16x16x32_bf16(aq, bk, (f32x4){0.f,0.f,0.f,0.f}, 0, 0, 0);
        }
    }
    // ---- mask + register softmax ----
    int lr[4], lc[4];
#pragma unroll
    for (int r = 0; r < 4; r++) {
        const int m = g * 4 + r;
        const int i = i0 + (m >> 2), j = j0 + (m & 3);
        lr[r] = min(max(i - 3, 0), HH - KW) - pr0;
        lc[r] = min(max(j - 3, 0), WW - KW) - pc0;
    }
    const float scale = 0.17677669529663687f;   // 1/sqrt(32)
#pragma unroll
    for (int t = 0; t < 7; t++) {
        const int col = t * 16 + li;
        const int pi = col / 10, pj = col - 10 * pi;
#pragma unroll
        for (int r = 0; r < 4; r++) {
            const bool valid = (col < PSZ) &&
                               ((unsigned)(pi - lr[r]) <= 6u) &&
                               ((unsigned)(pj - lc[r]) <= 6u);
            lg[t][r] = valid ? lg[t][r] * scale : -1e30f;
        }
    }
    f32x4 mx = lg[0], sm;
#pragma unroll
    for (int t = 1; t < 7; t++)
#pragma unroll
        for (int r = 0; r < 4; r++) mx[r] = fmaxf(mx[r], lg[t][r]);
#pragma unroll
    for (int off = 8; off; off >>= 1)
#pragma unroll
        for (int r = 0; r < 4; r++) mx[r] = fmaxf(mx[r], __shfl_xor(mx[r], off));
#pragma unroll
    for (int r = 0; r < 4; r++) sm[r] = 0.f;
#pragma unroll
    for (int t = 0; t < 7; t++)
#pragma unroll
        for (int r = 0; r < 4; r++) {
            lg[t][r] = __expf(lg[t][r] - mx[r]);
            sm[r] += lg[t][r];
        }
#pragma unroll
    for (int off = 8; off; off >>= 1)
#pragma unroll
        for (int r = 0; r < 4; r++) sm[r] += __shfl_xor(sm[r], off);
#pragma unroll
    for (int r = 0; r < 4; r++) sm[r] = 1.f / sm[r];

    // ---- P bf16 -> per-wave Pbuf (cols 112..127 zeroed); no barrier needed:
    // phase 2 reads only this wave's Pw (compiler inserts lgkmcnt wait) ----
    bf16_t* Pw = Pbuf + w * 16 * STR;
#pragma unroll
    for (int t = 0; t < 7; t++)
#pragma unroll
        for (int r = 0; r < 4; r++)
            Pw[(g * 4 + r) * STR + t * 16 + li] = (bf16_t)(lg[t][r] * sm[r]);
    *(bf16x4*)(Pw + (lane >> 2) * STR + NPAD + (lane & 3) * 4) = (bf16x4){0,0,0,0};

    // ---- attn phase 2: O[16][32] = P @ V^T (voff-table gathers) ----
    f32x4 oA[2] = {};
#pragma unroll
    for (int ks0 = 0; ks0 < 128; ks0 += 32) {
        const bf16x8 a = *(const bf16x8*)(Pw + li * STR + ks0 + g * 8);
        const i32x4 o0 = *(const i32x4*)&voff[ks0 + g * 8];
        const i32x4 o1 = *(const i32x4*)&voff[ks0 + g * 8 + 4];
#pragma unroll
        for (int t2 = 0; t2 < 2; t2++) {
            const int cb = ch + t2 * 16 + li;
            bf16x8 b;
            b[0] = vg[o0[0] + cb]; b[1] = vg[o0[1] + cb];
            b[2] = vg[o0[2] + cb]; b[3] = vg[o0[3] + cb];
            b[4] = vg[o1[0] + cb]; b[5] = vg[o1[1] + cb];
            b[6] = vg[o1[2] + cb]; b[7] = vg[o1[3] + cb];
            oA[t2] = __builtin_amdgcn_mfma_f32_16x16x32_bf16(a, b, oA[t2], 0, 0, 0);
        }
    }
    // ---- o -> o_s (cols ch..ch+31) ----
#pragma unroll
    for (int t2 = 0; t2 < 2; t2++)
#pragma unroll
        for (int r = 0; r < 4; r++)
            o_s[(g * 4 + r) * STR + ch + t2 * 16 + li] = (bf16_t)oA[t2][r];
    __syncthreads();                    // B2: o_s ready; Pbuf dead

    // ---- proj: x0s[16][128] = o @ proj_w^T + b; wave w -> cols w*32 ----
    {
        f32x4 acc[2] = {};
        mmaN<2>(o_s, STR, wb + W_PROJ + (w * 32) * CC, CC, CC, acc);
#pragma unroll
        for (int t = 0; t < 2; t++) {
            const int n = w * 32 + t * 16 + li;
            const float bb = proj_b[n];
#pragma unroll
            for (int r = 0; r < 4; r++)
                x0s[(g * 4 + r) * STR + n] = (bf16_t)(acc[t][r] + bb);
        }
    }
    __syncthreads();                    // B3: x0s ready

    // ---- fc1 + gelu: h1s[16][512] (overlays Pbuf); wave w -> cols w*128 ----
    {
        f32x4 acc[8] = {};
        mmaN<8>(x0s, STR, wb + W_FC1 + (w * 128) * CC, CC, CC, acc);
#pragma unroll
        for (int t = 0; t < 8; t++) {
            const int n = w * 128 + t * 16 + li;
            const float bb = fc1_b[n];
#pragma unroll
            for (int r = 0; r < 4; r++) {
                const int m = g * 4 + r;
                const float xv = acc[t][r] + bb;
                const float u = 0.7978845608028654f * (xv + 0.044715f * xv * xv * xv);
                const float e = __expf(2.f * u);
                const float gg = 0.5f * xv * (2.f - 2.f / (e + 1.f));
                h1s[m * H1S + n] = (bf16_t)gg;
            }
        }
    }
    __syncthreads();                    // B4: h1s ready

    // ---- fc2: fp32 out over the tile's own rows; wave w -> cols w*32 ----
    {
        f32x4 acc[2] = {};
        mmaN<2>(h1s, H1S, wb + W_FC2 + (w * 32) * (4 * CC), 4 * CC, 4 * CC, acc);
#pragma unroll
        for (int t = 0; t < 2; t++) {
            const int n = w * 32 + t * 16 + li;
            const float bb = fc2_b[n];
#pragma unroll
            for (int r = 0; r < 4; r++) {
                const int m = g * 4 + r;
                const int i = i0 + (m >> 2), j = j0 + (m & 3);
                float xv = acc[t][r] + bb;
                xv = fminf(fmaxf(xv, -1e4f), 1e4f);   // diagnostic clamp
                out[(i * WW + j) * CC + n] = xv;
            }
        }
    }
}

extern "C" void kernel_launch(void* const* d_in, const int* in_sizes, int n_in,
                              void* d_out, int out_size, void* d_ws, size_t ws_size,
                              hipStream_t stream) {
    const float* x      = (const float*)d_in[0];
    const float* qkv_w  = (const float*)d_in[1];
    const float* qkv_b  = (const float*)d_in[2];
    const float* proj_w = (const float*)d_in[3];
    const float* proj_b = (const float*)d_in[4];
    const float* fc1_w  = (const float*)d_in[5];
    const float* fc1_b  = (const float*)d_in[6];
    const float* fc2_w  = (const float*)d_in[7];
    const float* fc2_b  = (const float*)d_in[8];

    bf16_t* ws = (bf16_t*)d_ws;
    bf16_t* wb = ws;                    // bf16 weight slab (proj/fc1/fc2)
    bf16_t* qb = ws + W_TOT;            // [9216][128] bf16 planes
    bf16_t* kb = qb + PLANE;
    bf16_t* vb = kb + PLANE;
    float* out = (float*)d_out;

    k_qkv     <<<864, 256, 0, stream>>>(x, qkv_w, qkv_b, proj_w, fc1_w, fc2_w,
                                        wb, qb, kb, vb);
    k_attn_mlp<<<576, 256, 0, stream>>>(qb, kb, vb, wb,
                                        proj_b, fc1_b, fc2_b, out);
}

// Round 14
// 117.988 us; speedup vs baseline: 1.0729x; 1.0376x over previous
//
#include <hip/hip_runtime.h>

typedef __bf16 bf16_t;
typedef __bf16 bf16x8 __attribute__((ext_vector_type(8)));
typedef __bf16 bf16x4 __attribute__((ext_vector_type(4)));
typedef float f32x4 __attribute__((ext_vector_type(4)));
typedef int   i32x4 __attribute__((ext_vector_type(4)));

#define HH 96
#define WW 96
#define CC 128
#define HD 32
#define TOK (HH * WW)      // 9216
#define PLANE (TOK * CC)
#define KW 7

// bf16 weight slab (ws): qkv, proj, fc1, fc2
#define W_QKV  0
#define W_PROJ 49152
#define W_FC1  65536
#define W_FC2  131072
#define W_TOT  196608

#define PATCH 10
#define PSZ 100
#define NPAD 112            // 7 N-tiles of 16
#define STR 136             // LDS row stride (bf16)
#define H1S 520

// K2 LDS layout (bf16 elements)
#define L_P    0            // Pbuf 4*16*STR = 8704 ele -> h1s overlay (8320)
#define L_OS   8704         // o_s 16*STR
#define L_X0   10880        // x0s 16*STR
#define L_VOFF 13056        // 128 ints
#define L_TOT  13312        // 26624 B -> >=3 blocks/CU possible

// fp32 -> bf16x8
__device__ __forceinline__ bf16x8 cvt8(const float* __restrict__ p) {
    const f32x4 a = *(const f32x4*)p;
    const f32x4 b = *(const f32x4*)(p + 4);
    bf16x8 r;
    r[0] = (bf16_t)a[0]; r[1] = (bf16_t)a[1]; r[2] = (bf16_t)a[2]; r[3] = (bf16_t)a[3];
    r[4] = (bf16_t)b[0]; r[5] = (bf16_t)b[1]; r[6] = (bf16_t)b[2]; r[7] = (bf16_t)b[3];
    return r;
}

// NT-tile MFMA strip (bf16 A/W, K-contiguous rows, at tile origin).
// A-frag: lane holds A[lane&15][(lane>>4)*8+j]; B-frag: W[t*16+(lane&15)][...]
// C/D: reg r -> row (lane>>4)*4+r, col t*16+(lane&15)
template <int NT>
__device__ __forceinline__ void mmaN(const bf16_t* __restrict__ A, int lda,
                                     const bf16_t* __restrict__ W, int ldb,
                                     int K, f32x4* acc) {
    const int lane = threadIdx.x & 63;
    const bf16_t* ap = A + (lane & 15) * lda + ((lane >> 4) * 8);
    const bf16_t* bp = W + (lane & 15) * ldb + ((lane >> 4) * 8);
    for (int k0 = 0; k0 < K; k0 += 32) {
        bf16x8 a = *(const bf16x8*)(ap + k0);
#pragma unroll
        for (int t = 0; t < NT; t++) {
            bf16x8 b = *(const bf16x8*)(bp + t * 16 * ldb + k0);
            acc[t] = __builtin_amdgcn_mfma_f32_16x16x32_bf16(a, b, acc[t], 0, 0, 0);
        }
    }
}

// K0: cvt x + all 4 weight mats -> bf16. 1344 blocks (x: 294912 chunks of 4
// would be 1152 blocks; weights 192 blocks).
__global__ __launch_bounds__(256) void k_prep(const float* __restrict__ x,
                                              const float* __restrict__ qkv_w,
                                              const float* __restrict__ proj_w,
                                              const float* __restrict__ fc1_w,
                                              const float* __restrict__ fc2_w,
                                              bf16_t* __restrict__ xb,
                                              bf16_t* __restrict__ wb) {
    const int idx = blockIdx.x * 256 + threadIdx.x;
    const int NX = PLANE / 4;          // 294912 x-chunks
    const float* src;
    bf16_t* dst;
    int base;
    if (idx < NX) {                    // x -> xb
        base = idx * 4; src = x + base; dst = xb + base;
    } else {                           // weights -> slab
        base = (idx - NX) * 4;
        if (base >= W_TOT) return;
        dst = wb + base;
        if (base < W_PROJ)     src = qkv_w  + base;
        else if (base < W_FC1) src = proj_w + (base - W_PROJ);
        else if (base < W_FC2) src = fc1_w  + (base - W_FC1);
        else                   src = fc2_w  + (base - W_FC2);
    }
    const f32x4 a = *(const f32x4*)src;
    bf16x4 r;
    r[0] = (bf16_t)a[0]; r[1] = (bf16_t)a[1]; r[2] = (bf16_t)a[2]; r[3] = (bf16_t)a[3];
    *(bf16x4*)dst = r;
}

// K1: qkv = xb @ qkv_w.T + b, all-bf16 operands. 864 blocks.
// wave = 16 tokens x 64 cols (NT=4). q/k/v bf16 planes [tok][128].
__global__ __launch_bounds__(256) void k_qkv(const bf16_t* __restrict__ xb,
                                             const bf16_t* __restrict__ wb,
                                             const float* __restrict__ bias,
                                             bf16_t* __restrict__ qb,
                                             bf16_t* __restrict__ kb,
                                             bf16_t* __restrict__ vb) {
    const int wid = blockIdx.x * 4 + (threadIdx.x >> 6);   // 3456 waves
    const int m0 = (wid / 6) * 16;
    const int n0 = (wid % 6) * 64;
    const int lane = threadIdx.x & 63;
    const int g = lane >> 4, li = lane & 15;
    f32x4 acc[4] = {};
    mmaN<4>(xb + m0 * CC, CC, wb + W_QKV + n0 * CC, CC, CC, acc);
#pragma unroll
    for (int t = 0; t < 4; t++) {
        const int n = n0 + t * 16 + li;
        const float bb = bias[n];
        const int part = n >> 7, c = n & 127;
        bf16_t* dst = (part == 0) ? qb : (part == 1) ? kb : vb;
#pragma unroll
        for (int r = 0; r < 4; r++)
            dst[(m0 + g * 4 + r) * CC + c] = (bf16_t)(acc[t][r] + bb);
    }
}

// ===========================================================================
// K2: attn + proj + MLP per 4x4-token tile. 576 blocks x 256, one wave/head.
// (r13's proven kernel, unchanged.)
// ===========================================================================
__global__ __launch_bounds__(256, 3) void k_attn_mlp(
        const bf16_t* __restrict__ qb, const bf16_t* __restrict__ kg,
        const bf16_t* __restrict__ vg, const bf16_t* __restrict__ wb,
        const float* __restrict__ proj_b, const float* __restrict__ fc1_b,
        const float* __restrict__ fc2_b,  float* __restrict__ out) {
    __shared__ __align__(16) bf16_t smem[L_TOT];
    bf16_t* Pbuf = smem + L_P;
    bf16_t* o_s  = smem + L_OS;
    bf16_t* x0s  = smem + L_X0;
    bf16_t* h1s  = smem + L_P;          // overlays Pbuf after barrier 2
    int*    voff = (int*)(smem + L_VOFF);

    const int tid = threadIdx.x;
    const int w = tid >> 6, lane = tid & 63;
    const int g = lane >> 4, li = lane & 15;
    const int bid = blockIdx.x;
    const int i0 = (bid / 24) * 4, j0 = (bid % 24) * 4;
    const int pr0 = min(max(i0 - 3, 0), HH - PATCH);
    const int pc0 = min(max(j0 - 3, 0), WW - PATCH);
    const int ch = w * HD;

    if (tid < 128) {
        const int p = min(tid, PSZ - 1);
        const int pi = p / 10, pj = p - 10 * pi;
        voff[tid] = ((pr0 + pi) * WW + pc0 + pj) * CC;
    }
    __syncthreads();                    // B1: voff ready

    // ---- attn phase 1: logits[16][112] = Q @ K^T ----
    f32x4 lg[7];
    {
        const int qi = i0 + (li >> 2), qj = j0 + (li & 3);
        const bf16x8 aq = *(const bf16x8*)(qb + (qi * WW + qj) * CC + ch + g * 8);
#pragma unroll
        for (int t = 0; t < 7; t++) {
            const bf16x8 bk = *(const bf16x8*)(kg + voff[t * 16 + li] + ch + g * 8);
            lg[t] = __builtin_amdgcn_mfma_f32_16x16x32_bf16(aq, bk, (f32x4){0.f,0.f,0.f,0.f}, 0, 0, 0);
        }
    }
    // ---- mask + register softmax ----
    int lr[4], lc[4];
#pragma unroll
    for (int r = 0; r < 4; r++) {
        const int m = g * 4 + r;
        const int i = i0 + (m >> 2), j = j0 + (m & 3);
        lr[r] = min(max(i - 3, 0), HH - KW) - pr0;
        lc[r] = min(max(j - 3, 0), WW - KW) - pc0;
    }
    const float scale = 0.17677669529663687f;   // 1/sqrt(32)
#pragma unroll
    for (int t = 0; t < 7; t++) {
        const int col = t * 16 + li;
        const int pi = col / 10, pj = col - 10 * pi;
#pragma unroll
        for (int r = 0; r < 4; r++) {
            const bool valid = (col < PSZ) &&
                               ((unsigned)(pi - lr[r]) <= 6u) &&
                               ((unsigned)(pj - lc[r]) <= 6u);
            lg[t][r] = valid ? lg[t][r] * scale : -1e30f;
        }
    }
    f32x4 mx = lg[0], sm;
#pragma unroll
    for (int t = 1; t < 7; t++)
#pragma unroll
        for (int r = 0; r < 4; r++) mx[r] = fmaxf(mx[r], lg[t][r]);
#pragma unroll
    for (int off = 8; off; off >>= 1)
#pragma unroll
        for (int r = 0; r < 4; r++) mx[r] = fmaxf(mx[r], __shfl_xor(mx[r], off));
#pragma unroll
    for (int r = 0; r < 4; r++) sm[r] = 0.f;
#pragma unroll
    for (int t = 0; t < 7; t++)
#pragma unroll
        for (int r = 0; r < 4; r++) {
            lg[t][r] = __expf(lg[t][r] - mx[r]);
            sm[r] += lg[t][r];
        }
#pragma unroll
    for (int off = 8; off; off >>= 1)
#pragma unroll
        for (int r = 0; r < 4; r++) sm[r] += __shfl_xor(sm[r], off);
#pragma unroll
    for (int r = 0; r < 4; r++) sm[r] = 1.f / sm[r];

    // ---- P bf16 -> per-wave Pbuf (cols 112..127 zeroed) ----
    bf16_t* Pw = Pbuf + w * 16 * STR;
#pragma unroll
    for (int t = 0; t < 7; t++)
#pragma unroll
        for (int r = 0; r < 4; r++)
            Pw[(g * 4 + r) * STR + t * 16 + li] = (bf16_t)(lg[t][r] * sm[r]);
    *(bf16x4*)(Pw + (lane >> 2) * STR + NPAD + (lane & 3) * 4) = (bf16x4){0,0,0,0};

    // ---- attn phase 2: O[16][32] = P @ V^T (voff-table gathers) ----
    f32x4 oA[2] = {};
#pragma unroll
    for (int ks0 = 0; ks0 < 128; ks0 += 32) {
        const bf16x8 a = *(const bf16x8*)(Pw + li * STR + ks0 + g * 8);
        const i32x4 o0 = *(const i32x4*)&voff[ks0 + g * 8];
        const i32x4 o1 = *(const i32x4*)&voff[ks0 + g * 8 + 4];
#pragma unroll
        for (int t2 = 0; t2 < 2; t2++) {
            const int cb = ch + t2 * 16 + li;
            bf16x8 b;
            b[0] = vg[o0[0] + cb]; b[1] = vg[o0[1] + cb];
            b[2] = vg[o0[2] + cb]; b[3] = vg[o0[3] + cb];
            b[4] = vg[o1[0] + cb]; b[5] = vg[o1[1] + cb];
            b[6] = vg[o1[2] + cb]; b[7] = vg[o1[3] + cb];
            oA[t2] = __builtin_amdgcn_mfma_f32_16x16x32_bf16(a, b, oA[t2], 0, 0, 0);
        }
    }
#pragma unroll
    for (int t2 = 0; t2 < 2; t2++)
#pragma unroll
        for (int r = 0; r < 4; r++)
            o_s[(g * 4 + r) * STR + ch + t2 * 16 + li] = (bf16_t)oA[t2][r];
    __syncthreads();                    // B2: o_s ready; Pbuf dead

    // ---- proj: x0s[16][128] = o @ proj_w^T + b ----
    {
        f32x4 acc[2] = {};
        mmaN<2>(o_s, STR, wb + W_PROJ + (w * 32) * CC, CC, CC, acc);
#pragma unroll
        for (int t = 0; t < 2; t++) {
            const int n = w * 32 + t * 16 + li;
            const float bb = proj_b[n];
#pragma unroll
            for (int r = 0; r < 4; r++)
                x0s[(g * 4 + r) * STR + n] = (bf16_t)(acc[t][r] + bb);
        }
    }
    __syncthreads();                    // B3: x0s ready

    // ---- fc1 + gelu: h1s[16][512] ----
    {
        f32x4 acc[8] = {};
        mmaN<8>(x0s, STR, wb + W_FC1 + (w * 128) * CC, CC, CC, acc);
#pragma unroll
        for (int t = 0; t < 8; t++) {
            const int n = w * 128 + t * 16 + li;
            const float bb = fc1_b[n];
#pragma unroll
            for (int r = 0; r < 4; r++) {
                const int m = g * 4 + r;
                const float xv = acc[t][r] + bb;
                const float u = 0.7978845608028654f * (xv + 0.044715f * xv * xv * xv);
                const float e = __expf(2.f * u);
                const float gg = 0.5f * xv * (2.f - 2.f / (e + 1.f));
                h1s[m * H1S + n] = (bf16_t)gg;
            }
        }
    }
    __syncthreads();                    // B4: h1s ready

    // ---- fc2: fp32 out over the tile's own rows ----
    {
        f32x4 acc[2] = {};
        mmaN<2>(h1s, H1S, wb + W_FC2 + (w * 32) * (4 * CC), 4 * CC, 4 * CC, acc);
#pragma unroll
        for (int t = 0; t < 2; t++) {
            const int n = w * 32 + t * 16 + li;
            const float bb = fc2_b[n];
#pragma unroll
            for (int r = 0; r < 4; r++) {
                const int m = g * 4 + r;
                const int i = i0 + (m >> 2), j = j0 + (m & 3);
                float xv = acc[t][r] + bb;
                xv = fminf(fmaxf(xv, -1e4f), 1e4f);   // diagnostic clamp
                out[(i * WW + j) * CC + n] = xv;
            }
        }
    }
}

extern "C" void kernel_launch(void* const* d_in, const int* in_sizes, int n_in,
                              void* d_out, int out_size, void* d_ws, size_t ws_size,
                              hipStream_t stream) {
    const float* x      = (const float*)d_in[0];
    const float* qkv_w  = (const float*)d_in[1];
    const float* qkv_b  = (const float*)d_in[2];
    const float* proj_w = (const float*)d_in[3];
    const float* proj_b = (const float*)d_in[4];
    const float* fc1_w  = (const float*)d_in[5];
    const float* fc1_b  = (const float*)d_in[6];
    const float* fc2_w  = (const float*)d_in[7];
    const float* fc2_b  = (const float*)d_in[8];

    bf16_t* ws = (bf16_t*)d_ws;
    bf16_t* wb = ws;                    // bf16 weight slab
    bf16_t* xb = ws + W_TOT;            // x bf16 plane
    bf16_t* qb = xb + PLANE;            // q/k/v bf16 planes
    bf16_t* kb = qb + PLANE;
    bf16_t* vb = kb + PLANE;
    float* out = (float*)d_out;

    // prep grid: x chunks (294912/256=1152 blocks) + weights (192) = 1344
    k_prep    <<<1344, 256, 0, stream>>>(x, qkv_w, proj_w, fc1_w, fc2_w, xb, wb);
    k_qkv     <<<864,  256, 0, stream>>>(xb, wb, qkv_b, qb, kb, vb);
    k_attn_mlp<<<576,  256, 0, stream>>>(qb, kb, vb, wb,
                                         proj_b, fc1_b, fc2_b, out);
}